// Round 11
// baseline (33.722 us; speedup 1.0000x reference)
//
#include <hip/hip_runtime.h>

#define DH 256
#define LQ 256

typedef __bf16 bf16x8 __attribute__((ext_vector_type(8)));
typedef __bf16 bf16x4 __attribute__((ext_vector_type(4)));
typedef __bf16 bf16x2 __attribute__((ext_vector_type(2)));
typedef float  f32x4  __attribute__((ext_vector_type(4)));

__device__ __forceinline__ bf16x8 cvt2(float4 a, float4 b) {
    bf16x8 v;
    v[0] = (__bf16)a.x; v[1] = (__bf16)a.y; v[2] = (__bf16)a.z; v[3] = (__bf16)a.w;
    v[4] = (__bf16)b.x; v[5] = (__bf16)b.y; v[6] = (__bf16)b.z; v[7] = (__bf16)b.w;
    return v;
}

// ---- stage a 32-row x 256-col panel from f32 row-major global into LDS bf16 [32][264]
__device__ __forceinline__ void stage32f(const float* __restrict__ src, int row0,
                                         __bf16 (*dst)[264], int tid) {
    const int r = tid >> 3;
    #pragma unroll
    for (int c = 0; c < 4; ++c) {
        const int ch = (tid & 7) + 8 * c;
        const float* p = src + (row0 + r) * DH + ch * 8;
        *(bf16x8*)&dst[r][ch * 8] = cvt2(*(const float4*)p, *(const float4*)(p + 4));
    }
}
// ---- same but bf16 source
__device__ __forceinline__ void stage32h(const __bf16* __restrict__ src, int row0,
                                         __bf16 (*dst)[264], int tid) {
    const int r = tid >> 3;
    #pragma unroll
    for (int c = 0; c < 4; ++c) {
        const int ch = (tid & 7) + 8 * c;
        *(bf16x8*)&dst[r][ch * 8] = *(const bf16x8*)&src[(row0 + r) * DH + ch * 8];
    }
}
// ---- transposed stage: dst[tok_local][h] <- src[(b*256+h)*256 + tok0+tok_local], h = tid
__device__ __forceinline__ void stageT(const __bf16* __restrict__ src, int b, int tok0,
                                       __bf16 (*dst)[264], int tid) {
    const __bf16* p = src + (((b << 8) + tid) << 8) + tok0;
    bf16x8 v0 = *(const bf16x8*)(p);
    bf16x8 v1 = *(const bf16x8*)(p + 8);
    bf16x8 v2 = *(const bf16x8*)(p + 16);
    bf16x8 v3 = *(const bf16x8*)(p + 24);
    #pragma unroll
    for (int t = 0; t < 8; ++t) {
        dst[t][tid]      = v0[t];
        dst[8 + t][tid]  = v1[t];
        dst[16 + t][tid] = v2[t];
        dst[24 + t][tid] = v3[t];
    }
}
// ---- MFMA 16x16x32 fragment from LDS panel
__device__ __forceinline__ bf16x8 frag(const __bf16 (*m)[264], int r0, int ks, int lane) {
    return *(const bf16x8*)&m[r0 + (lane & 15)][ks * 32 + ((lane >> 4) << 3)];
}

// ---------- K1 (fused): recompute rep stripe; write rep (nb==0); dep/head; Ed/Eh ----------
// Block = 32 toks (mb) x 32 h (nb). Phase A: rep[32][256] from X,Wfc in 8 K-chunks
// (reg-prefetch dbuf). Phase B: dep/head GEMM from LDS rep. rep bitwise-identical
// across nb -> designated writer nb==0 stores rep_bf/rep_t.
__global__ __launch_bounds__(256) void k_front(
    const float* __restrict__ X, const float* __restrict__ Wfc, const float* __restrict__ bfc,
    const float* __restrict__ W1, const float* __restrict__ W2, const float* __restrict__ b1,
    __bf16* __restrict__ rep_bf, __bf16* __restrict__ rep_t,
    float* __restrict__ Ed_t, float* __restrict__ Eh_t)
{
    __shared__ __bf16 repl[32][264];
    __shared__ __bf16 arena[2][32][264];   // A: [0]=X panel, [1]=Wfc chunk; B: [0]=W1, [1]=W2
    const int tid = threadIdx.x, lane = tid & 63, wid = tid >> 6;
    const int mb = blockIdx.x >> 3, nb = blockIdx.x & 7;
    const int r0 = mb * 32, c0 = nb * 32;
    const int b = r0 >> 8, tok0 = r0 & 255;
    const int wr = (wid >> 1) * 16, wc = (wid & 1) * 16;
    const int sr = tid >> 3;

    // prefetch Wfc chunk 0 into regs
    float4 pf[4][2];
    #pragma unroll
    for (int c = 0; c < 4; ++c) {
        const float* p = Wfc + sr * DH + ((tid & 7) + 8 * c) * 8;
        pf[c][0] = *(const float4*)p; pf[c][1] = *(const float4*)(p + 4);
    }
    stage32f(X, r0, arena[0], tid);

    for (int kc = 0; kc < 8; ++kc) {
        __syncthreads();                       // prev chunk's MFMA done; X panel staged
        #pragma unroll
        for (int c = 0; c < 4; ++c)
            *(bf16x8*)&arena[1][sr][((tid & 7) + 8 * c) * 8] = cvt2(pf[c][0], pf[c][1]);
        if (kc < 7) {
            #pragma unroll
            for (int c = 0; c < 4; ++c) {
                const float* p = Wfc + ((kc + 1) * 32 + sr) * DH + ((tid & 7) + 8 * c) * 8;
                pf[c][0] = *(const float4*)p; pf[c][1] = *(const float4*)(p + 4);
            }
        }
        __syncthreads();
        f32x4 acc = {0.f, 0.f, 0.f, 0.f};
        #pragma unroll
        for (int ks = 0; ks < 8; ++ks)
            acc = __builtin_amdgcn_mfma_f32_16x16x32_bf16(frag(arena[0], wr, ks, lane),
                                                          frag(arena[1], wc, ks, lane), acc, 0, 0, 0);
        const int kcol = kc * 32 + wc + (lane & 15);   // rep channel index
        const int trow = wr + ((lane >> 4) << 2);      // block-local token row
        const float bv = bfc[kcol];
        bf16x4 pk;
        #pragma unroll
        for (int r = 0; r < 4; ++r) {
            float v = acc[r] + bv;
            v = (v > 0.f) ? v : (__expf(v) - 1.f);
            __bf16 h = (__bf16)v;
            repl[trow + r][kcol] = h;
            pk[r] = h;
        }
        if (nb == 0) {                                 // designated writer (bitwise-identical)
            #pragma unroll
            for (int r = 0; r < 4; ++r)
                rep_bf[(r0 + trow + r) * DH + kcol] = pk[r];
            *(bf16x4*)(rep_t + ((b << 8) + kcol) * LQ + tok0 + trow) = pk;
        }
    }
    __syncthreads();                                   // repl complete; arena free

    // phase B: dep/head for this block's 32 h's
    stage32f(W1, c0, arena[0], tid);
    stage32f(W2, c0, arena[1], tid);
    __syncthreads();
    f32x4 ad = {0.f, 0.f, 0.f, 0.f}, ah = {0.f, 0.f, 0.f, 0.f};
    #pragma unroll
    for (int ks = 0; ks < 8; ++ks) {
        bf16x8 a = frag(repl, wr, ks, lane);
        ad = __builtin_amdgcn_mfma_f32_16x16x32_bf16(a, frag(arena[0], wc, ks, lane), ad, 0, 0, 0);
        ah = __builtin_amdgcn_mfma_f32_16x16x32_bf16(a, frag(arena[1], wc, ks, lane), ah, 0, 0, 0);
    }
    const int col = c0 + wc + (lane & 15);
    const int row = r0 + wr + ((lane >> 4) << 2);
    const int tok = row & 255;
    const float bb = b1[col];
    f32x4 ed, eh;
    #pragma unroll
    for (int r = 0; r < 4; ++r) {
        ed[r] = __expf(0.4f * (ad[r] + bb));   // 2/C = 0.4
        eh[r] = __expf(0.4f * ah[r]);
    }
    *(f32x4*)(Ed_t + ((b << 8) + col) * LQ + tok) = ed;
    *(f32x4*)(Eh_t + ((b << 8) + col) * LQ + tok) = eh;
}

// ---------- K2: per-(b,h) masked channel-softmax; w_ij = exp2(A1*rcp(Ed_j*Eh_i+1)) ----------
__global__ __launch_bounds__(128) void k_attn(
    const float* __restrict__ Ed_t, const float* __restrict__ Eh_t,
    const __bf16* __restrict__ rep_t, __bf16* __restrict__ attn_t)
{
    __shared__ float Ed[256];
    __shared__ float Rp[256];
    const int bh = blockIdx.x;
    const int tid = threadIdx.x, lane = tid & 63, wv = tid >> 6;
    {
        const int j0 = tid * 2;
        float2 d = *(const float2*)(Ed_t + bh * LQ + j0);
        bf16x2 rv = *(const bf16x2*)(rep_t + bh * LQ + j0);
        Ed[j0] = d.x; Ed[j0 + 1] = d.y;
        Rp[j0] = (float)rv[0]; Rp[j0 + 1] = (float)rv[1];
    }
    __syncthreads();
    const float A1 = -14.4269504f;             // -2C*log2(e)
    #pragma unroll
    for (int t = 0; t < 2; ++t) {
        const int w = wv ? (t ? 2 : 1) : (t ? 3 : 0);
        const int i = w * 64 + lane;
        const float Eh = Eh_t[bh * LQ + i];
        float s = 0.f, acc = 0.f;
        for (int jb = 248; jb >= (w + 1) * 64; jb -= 8) {
            #pragma unroll
            for (int u = 0; u < 8; ++u) {
                const int j = jb + u;
                float r = __builtin_amdgcn_rcpf(fmaf(Ed[j], Eh, 1.f));
                float e = __builtin_amdgcn_exp2f(A1 * r);
                s += e;
                acc = fmaf(e, Rp[j], acc);
            }
        }
        for (int jb = w * 64 + 56; jb >= w * 64; jb -= 8) {
            #pragma unroll
            for (int u = 0; u < 8; ++u) {
                const int j = jb + u;
                float r = __builtin_amdgcn_rcpf(fmaf(Ed[j], Eh, 1.f));
                float e = __builtin_amdgcn_exp2f(A1 * r);
                e = (j > i) ? e : 0.f;
                s += e;
                acc = fmaf(e, Rp[j], acc);
            }
        }
        attn_t[bh * LQ + i] = (__bf16)(acc / (s + 1e-20f));
    }
}

// ---------- K3: gate = sigmoid(rep@Wf1^T + attn@Wf2^T + bf); blend; mask ----------
__global__ __launch_bounds__(256) void k_gate(
    const __bf16* __restrict__ rep_bf, const __bf16* __restrict__ attn_t,
    const float* __restrict__ Wf1, const float* __restrict__ Wf2,
    const float* __restrict__ bfv, const float* __restrict__ rmask,
    float* __restrict__ out)
{
    __shared__ __bf16 Ra[32][264];
    __shared__ __bf16 Aa[32][264];
    __shared__ __bf16 U1[32][264];
    __shared__ __bf16 U2[32][264];
    const int tid = threadIdx.x, lane = tid & 63, wid = tid >> 6;
    const int mb = blockIdx.x >> 3, nb = blockIdx.x & 7;
    const int r0 = mb * 32, c0 = nb * 32;
    const int b = r0 >> 8, tok0 = r0 & 255;
    stage32h(rep_bf, r0, Ra, tid);
    stageT(attn_t, b, tok0, Aa, tid);
    stage32f(Wf1, c0, U1, tid);
    stage32f(Wf2, c0, U2, tid);
    __syncthreads();
    const int wr = (wid >> 1) * 16, wc = (wid & 1) * 16;
    f32x4 acc = {0.f, 0.f, 0.f, 0.f};
    #pragma unroll
    for (int ks = 0; ks < 8; ++ks) {
        acc = __builtin_amdgcn_mfma_f32_16x16x32_bf16(frag(Ra, wr, ks, lane),
                                                      frag(U1, wc, ks, lane), acc, 0, 0, 0);
        acc = __builtin_amdgcn_mfma_f32_16x16x32_bf16(frag(Aa, wr, ks, lane),
                                                      frag(U2, wc, ks, lane), acc, 0, 0, 0);
    }
    const int col = c0 + wc + (lane & 15);
    const int lr0 = wr + ((lane >> 4) << 2);
    const float bb = bfv[col];
    #pragma unroll
    for (int r = 0; r < 4; ++r) {
        const int lr = lr0 + r, rr = r0 + lr;
        float z = acc[r] + bb;
        float g = 1.f / (1.f + __expf(-z));
        float rv = (float)Ra[lr][col];
        float av = (float)Aa[lr][col];
        out[rr * DH + col] = (g * rv + (1.f - g) * av) * rmask[rr];
    }
}

extern "C" void kernel_launch(void* const* d_in, const int* in_sizes, int n_in,
                              void* d_out, int out_size, void* d_ws, size_t ws_size,
                              hipStream_t stream) {
    const float* x    = (const float*)d_in[0];
    const float* rmsk = (const float*)d_in[1];
    const float* fc_w = (const float*)d_in[2];
    const float* fc_b = (const float*)d_in[3];
    const float* w1   = (const float*)d_in[4];
    const float* w2   = (const float*)d_in[5];
    const float* b1   = (const float*)d_in[6];
    const float* wf1  = (const float*)d_in[7];
    const float* wf2  = (const float*)d_in[8];
    const float* bfb  = (const float*)d_in[9];

    char* ws = (char*)d_ws;
    __bf16* rep_bf  = (__bf16*)(ws);                  // 512 KB row-major
    __bf16* rep_t   = (__bf16*)(ws + (1u << 19));     // 512 KB bh-major
    __bf16* attn_t  = (__bf16*)(ws + (2u << 19));     // 512 KB bh-major
    float*  Ed_t    = (float*)(ws + (3u << 19));      // 1 MB bh-major
    float*  Eh_t    = (float*)(ws + (5u << 19));      // 1 MB bh-major

    k_front<<<dim3(256), dim3(256), 0, stream>>>(x, fc_w, fc_b, w1, w2, b1,
                                                 rep_bf, rep_t, Ed_t, Eh_t);
    k_attn<<<dim3(1024), dim3(128), 0, stream>>>(Ed_t, Eh_t, rep_t, attn_t);
    k_gate<<<dim3(256), dim3(256), 0, stream>>>(rep_bf, attn_t, wf1, wf2, bfb, rmsk,
                                                (float*)d_out);
}

// Round 12
// 32.373 us; speedup vs baseline: 1.0417x; 1.0417x over previous
//
#include <hip/hip_runtime.h>

#define DH 256
#define LQ 256

typedef __bf16 bf16x8 __attribute__((ext_vector_type(8)));
typedef __bf16 bf16x4 __attribute__((ext_vector_type(4)));
typedef __bf16 bf16x2 __attribute__((ext_vector_type(2)));
typedef float  f32x4  __attribute__((ext_vector_type(4)));

__device__ __forceinline__ bf16x8 cvt2(float4 a, float4 b) {
    bf16x8 v;
    v[0] = (__bf16)a.x; v[1] = (__bf16)a.y; v[2] = (__bf16)a.z; v[3] = (__bf16)a.w;
    v[4] = (__bf16)b.x; v[5] = (__bf16)b.y; v[6] = (__bf16)b.z; v[7] = (__bf16)b.w;
    return v;
}

// ---- 16-row x 256-col panel, f32 source, 128 threads: 8 thr/row x 4 chunks ----
__device__ __forceinline__ void stage16f(const float* __restrict__ src, int row0,
                                         __bf16 (*dst)[264], int tid) {
    const int r = tid >> 3;
    #pragma unroll
    for (int c = 0; c < 4; ++c) {
        const int ch = (tid & 7) + 8 * c;
        const float* p = src + (row0 + r) * DH + ch * 8;
        *(bf16x8*)&dst[r][ch * 8] = cvt2(*(const float4*)p, *(const float4*)(p + 4));
    }
}
// ---- 16-row panel, bf16 source, 128 threads ----
__device__ __forceinline__ void stage16h(const __bf16* __restrict__ src, int row0,
                                         __bf16 (*dst)[264], int tid) {
    const int r = tid >> 3;
    #pragma unroll
    for (int c = 0; c < 4; ++c) {
        const int ch = (tid & 7) + 8 * c;
        *(bf16x8*)&dst[r][ch * 8] = *(const bf16x8*)&src[(row0 + r) * DH + ch * 8];
    }
}
// ---- 32-row x 256-col panel, f32 source, 128 threads: 4 thr/row x 8 chunks ----
__device__ __forceinline__ void stage32w(const float* __restrict__ src, int row0,
                                         __bf16 (*dst)[264], int tid) {
    const int r = tid >> 2;
    #pragma unroll
    for (int c = 0; c < 8; ++c) {
        const int ch = (tid & 3) + 4 * c;
        const float* p = src + (row0 + r) * DH + ch * 8;
        *(bf16x8*)&dst[r][ch * 8] = cvt2(*(const float4*)p, *(const float4*)(p + 4));
    }
}
// ---- transposed 16-tok stage from bh-major: dst[tok][h], 128 threads x 2 h's ----
__device__ __forceinline__ void stageT16(const __bf16* __restrict__ src, int b, int tok0,
                                         __bf16 (*dst)[264], int tid) {
    #pragma unroll
    for (int g = 0; g < 2; ++g) {
        const int h = tid + g * 128;
        const __bf16* p = src + (((b << 8) + h) << 8) + tok0;
        bf16x8 v0 = *(const bf16x8*)(p);
        bf16x8 v1 = *(const bf16x8*)(p + 8);
        #pragma unroll
        for (int t = 0; t < 8; ++t) {
            dst[t][h]     = v0[t];
            dst[8 + t][h] = v1[t];
        }
    }
}
// ---- MFMA 16x16x32 fragment from LDS panel ----
__device__ __forceinline__ bf16x8 frag(const __bf16 (*m)[264], int r0, int ks, int lane) {
    return *(const bf16x8*)&m[r0 + (lane & 15)][ks * 32 + ((lane >> 4) << 3)];
}

// ---------- K1: rep = elu(X @ Wfc^T + b) -> rep_bf (row-major) + rep_t (bh-major) ----------
// 512 blocks x 128 thr: 16-tok x 32-col tile, 2 waves (one 16x16 tile each), 2 blocks/CU.
__global__ __launch_bounds__(128) void k_fc(
    const float* __restrict__ X, const float* __restrict__ Wfc, const float* __restrict__ bfc,
    __bf16* __restrict__ rep_bf, __bf16* __restrict__ rep_t)
{
    __shared__ __bf16 Xa[16][264];
    __shared__ __bf16 Wb[32][264];
    const int tid = threadIdx.x, lane = tid & 63, wid = tid >> 6;
    const int mb = blockIdx.x >> 3, nb = blockIdx.x & 7;
    const int r0 = mb * 16, c0 = nb * 32;
    stage16f(X, r0, Xa, tid);
    stage32w(Wfc, c0, Wb, tid);
    __syncthreads();
    const int wc = wid * 16;
    f32x4 acc = {0.f, 0.f, 0.f, 0.f};
    #pragma unroll
    for (int ks = 0; ks < 8; ++ks)
        acc = __builtin_amdgcn_mfma_f32_16x16x32_bf16(frag(Xa, 0, ks, lane),
                                                      frag(Wb, wc, ks, lane), acc, 0, 0, 0);
    const int col = c0 + wc + (lane & 15);
    const int row = r0 + ((lane >> 4) << 2);
    const int b = row >> 8, tok = row & 255;
    const float bv = bfc[col];
    bf16x4 pk;
    #pragma unroll
    for (int r = 0; r < 4; ++r) {
        float v = acc[r] + bv;
        v = (v > 0.f) ? v : (__expf(v) - 1.f);
        __bf16 h = (__bf16)v;
        rep_bf[(row + r) * DH + col] = h;
        pk[r] = h;
    }
    *(bf16x4*)(rep_t + ((b << 8) + col) * LQ + tok) = pk;
}

// ---------- K2: Ed = exp(0.4*(rep@W1^T+b1)), Eh = exp(0.4*rep@W2^T)  (bh-major f32) ----------
__global__ __launch_bounds__(128) void k_dephead(
    const __bf16* __restrict__ rep_bf, const float* __restrict__ W1, const float* __restrict__ W2,
    const float* __restrict__ b1, float* __restrict__ Ed_t, float* __restrict__ Eh_t)
{
    __shared__ __bf16 Ra[16][264];
    __shared__ __bf16 U1[32][264];
    __shared__ __bf16 U2[32][264];
    const int tid = threadIdx.x, lane = tid & 63, wid = tid >> 6;
    const int mb = blockIdx.x >> 3, nb = blockIdx.x & 7;
    const int r0 = mb * 16, c0 = nb * 32;
    stage16h(rep_bf, r0, Ra, tid);
    stage32w(W1, c0, U1, tid);
    stage32w(W2, c0, U2, tid);
    __syncthreads();
    const int wc = wid * 16;
    f32x4 ad = {0.f, 0.f, 0.f, 0.f}, ah = {0.f, 0.f, 0.f, 0.f};
    #pragma unroll
    for (int ks = 0; ks < 8; ++ks) {
        bf16x8 a = frag(Ra, 0, ks, lane);
        ad = __builtin_amdgcn_mfma_f32_16x16x32_bf16(a, frag(U1, wc, ks, lane), ad, 0, 0, 0);
        ah = __builtin_amdgcn_mfma_f32_16x16x32_bf16(a, frag(U2, wc, ks, lane), ah, 0, 0, 0);
    }
    const int col = c0 + wc + (lane & 15);
    const int row = r0 + ((lane >> 4) << 2);
    const int b = row >> 8, tok = row & 255;
    const float bb = b1[col];
    f32x4 ed, eh;
    #pragma unroll
    for (int r = 0; r < 4; ++r) {
        ed[r] = __expf(0.4f * (ad[r] + bb));   // 2/C = 0.4
        eh[r] = __expf(0.4f * ah[r]);
    }
    *(f32x4*)(Ed_t + ((b << 8) + col) * LQ + tok) = ed;
    *(f32x4*)(Eh_t + ((b << 8) + col) * LQ + tok) = eh;
}

// ---------- K3: per-(b,h) masked channel-softmax; w_ij = exp2(A1*rcp(Ed_j*Eh_i+1)) ----------
// (byte-identical to round 10)
__global__ __launch_bounds__(128) void k_attn(
    const float* __restrict__ Ed_t, const float* __restrict__ Eh_t,
    const __bf16* __restrict__ rep_t, __bf16* __restrict__ attn_t)
{
    __shared__ float Ed[256];
    __shared__ float Rp[256];
    const int bh = blockIdx.x;
    const int tid = threadIdx.x, lane = tid & 63, wv = tid >> 6;
    {
        const int j0 = tid * 2;
        float2 d = *(const float2*)(Ed_t + bh * LQ + j0);
        bf16x2 rv = *(const bf16x2*)(rep_t + bh * LQ + j0);
        Ed[j0] = d.x; Ed[j0 + 1] = d.y;
        Rp[j0] = (float)rv[0]; Rp[j0 + 1] = (float)rv[1];
    }
    __syncthreads();
    const float A1 = -14.4269504f;             // -2C*log2(e)
    #pragma unroll
    for (int t = 0; t < 2; ++t) {
        const int w = wv ? (t ? 2 : 1) : (t ? 3 : 0);
        const int i = w * 64 + lane;
        const float Eh = Eh_t[bh * LQ + i];
        float s = 0.f, acc = 0.f;
        for (int jb = 248; jb >= (w + 1) * 64; jb -= 8) {
            #pragma unroll
            for (int u = 0; u < 8; ++u) {
                const int j = jb + u;
                float r = __builtin_amdgcn_rcpf(fmaf(Ed[j], Eh, 1.f));
                float e = __builtin_amdgcn_exp2f(A1 * r);
                s += e;
                acc = fmaf(e, Rp[j], acc);
            }
        }
        for (int jb = w * 64 + 56; jb >= w * 64; jb -= 8) {
            #pragma unroll
            for (int u = 0; u < 8; ++u) {
                const int j = jb + u;
                float r = __builtin_amdgcn_rcpf(fmaf(Ed[j], Eh, 1.f));
                float e = __builtin_amdgcn_exp2f(A1 * r);
                e = (j > i) ? e : 0.f;
                s += e;
                acc = fmaf(e, Rp[j], acc);
            }
        }
        attn_t[bh * LQ + i] = (__bf16)(acc / (s + 1e-20f));
    }
}

// ---------- K4: gate = sigmoid(rep@Wf1^T + attn@Wf2^T + bf); blend; mask ----------
__global__ __launch_bounds__(128) void k_gate(
    const __bf16* __restrict__ rep_bf, const __bf16* __restrict__ attn_t,
    const float* __restrict__ Wf1, const float* __restrict__ Wf2,
    const float* __restrict__ bfv, const float* __restrict__ rmask,
    float* __restrict__ out)
{
    __shared__ __bf16 Ra[16][264];
    __shared__ __bf16 Aa[16][264];
    __shared__ __bf16 U1[32][264];
    __shared__ __bf16 U2[32][264];
    const int tid = threadIdx.x, lane = tid & 63, wid = tid >> 6;
    const int mb = blockIdx.x >> 3, nb = blockIdx.x & 7;
    const int r0 = mb * 16, c0 = nb * 32;
    const int b = r0 >> 8, tok0 = r0 & 255;
    stage16h(rep_bf, r0, Ra, tid);
    stageT16(attn_t, b, tok0, Aa, tid);
    stage32w(Wf1, c0, U1, tid);
    stage32w(Wf2, c0, U2, tid);
    __syncthreads();
    const int wc = wid * 16;
    f32x4 acc = {0.f, 0.f, 0.f, 0.f};
    #pragma unroll
    for (int ks = 0; ks < 8; ++ks) {
        acc = __builtin_amdgcn_mfma_f32_16x16x32_bf16(frag(Ra, 0, ks, lane),
                                                      frag(U1, wc, ks, lane), acc, 0, 0, 0);
        acc = __builtin_amdgcn_mfma_f32_16x16x32_bf16(frag(Aa, 0, ks, lane),
                                                      frag(U2, wc, ks, lane), acc, 0, 0, 0);
    }
    const int col = c0 + wc + (lane & 15);
    const int lr0 = (lane >> 4) << 2;
    const float bb = bfv[col];
    #pragma unroll
    for (int r = 0; r < 4; ++r) {
        const int lr = lr0 + r, rr = r0 + lr;
        float z = acc[r] + bb;
        float g = 1.f / (1.f + __expf(-z));
        float rv = (float)Ra[lr][col];
        float av = (float)Aa[lr][col];
        out[rr * DH + col] = (g * rv + (1.f - g) * av) * rmask[rr];
    }
}

extern "C" void kernel_launch(void* const* d_in, const int* in_sizes, int n_in,
                              void* d_out, int out_size, void* d_ws, size_t ws_size,
                              hipStream_t stream) {
    const float* x    = (const float*)d_in[0];
    const float* rmsk = (const float*)d_in[1];
    const float* fc_w = (const float*)d_in[2];
    const float* fc_b = (const float*)d_in[3];
    const float* w1   = (const float*)d_in[4];
    const float* w2   = (const float*)d_in[5];
    const float* b1   = (const float*)d_in[6];
    const float* wf1  = (const float*)d_in[7];
    const float* wf2  = (const float*)d_in[8];
    const float* bfb  = (const float*)d_in[9];

    char* ws = (char*)d_ws;
    __bf16* rep_bf  = (__bf16*)(ws);                  // 512 KB row-major
    __bf16* rep_t   = (__bf16*)(ws + (1u << 19));     // 512 KB bh-major
    __bf16* attn_t  = (__bf16*)(ws + (2u << 19));     // 512 KB bh-major
    float*  Ed_t    = (float*)(ws + (3u << 19));      // 1 MB bh-major
    float*  Eh_t    = (float*)(ws + (5u << 19));      // 1 MB bh-major

    k_fc<<<dim3(512), dim3(128), 0, stream>>>(x, fc_w, fc_b, rep_bf, rep_t);
    k_dephead<<<dim3(512), dim3(128), 0, stream>>>(rep_bf, w1, w2, b1, Ed_t, Eh_t);
    k_attn<<<dim3(1024), dim3(128), 0, stream>>>(Ed_t, Eh_t, rep_t, attn_t);
    k_gate<<<dim3(512), dim3(128), 0, stream>>>(rep_bf, attn_t, wf1, wf2, bfb, rmsk,
                                                (float*)d_out);
}

// Round 13
// 30.970 us; speedup vs baseline: 1.0889x; 1.0453x over previous
//
#include <hip/hip_runtime.h>

#define DH 256
#define LQ 256

typedef __bf16 bf16x8 __attribute__((ext_vector_type(8)));
typedef __bf16 bf16x4 __attribute__((ext_vector_type(4)));
typedef float  f32x4  __attribute__((ext_vector_type(4)));

__device__ __forceinline__ bf16x8 cvt2(float4 a, float4 b) {
    bf16x8 v;
    v[0] = (__bf16)a.x; v[1] = (__bf16)a.y; v[2] = (__bf16)a.z; v[3] = (__bf16)a.w;
    v[4] = (__bf16)b.x; v[5] = (__bf16)b.y; v[6] = (__bf16)b.z; v[7] = (__bf16)b.w;
    return v;
}

// ---- stage a 32-row x 256-col panel from f32 row-major global into LDS bf16 [32][264]
__device__ __forceinline__ void stage32f(const float* __restrict__ src, int row0,
                                         __bf16 (*dst)[264], int tid) {
    const int r = tid >> 3;
    #pragma unroll
    for (int c = 0; c < 4; ++c) {
        const int ch = (tid & 7) + 8 * c;
        const float* p = src + (row0 + r) * DH + ch * 8;
        *(bf16x8*)&dst[r][ch * 8] = cvt2(*(const float4*)p, *(const float4*)(p + 4));
    }
}
// ---- same but bf16 source
__device__ __forceinline__ void stage32h(const __bf16* __restrict__ src, int row0,
                                         __bf16 (*dst)[264], int tid) {
    const int r = tid >> 3;
    #pragma unroll
    for (int c = 0; c < 4; ++c) {
        const int ch = (tid & 7) + 8 * c;
        *(bf16x8*)&dst[r][ch * 8] = *(const bf16x8*)&src[(row0 + r) * DH + ch * 8];
    }
}
// ---- transposed stage: dst[tok_local][h] <- src[(b*256+h)*256 + tok0+tok_local], h = tid
__device__ __forceinline__ void stageT(const __bf16* __restrict__ src, int b, int tok0,
                                       __bf16 (*dst)[264], int tid) {
    const __bf16* p = src + (((b << 8) + tid) << 8) + tok0;
    bf16x8 v0 = *(const bf16x8*)(p);
    bf16x8 v1 = *(const bf16x8*)(p + 8);
    bf16x8 v2 = *(const bf16x8*)(p + 16);
    bf16x8 v3 = *(const bf16x8*)(p + 24);
    #pragma unroll
    for (int t = 0; t < 8; ++t) {
        dst[t][tid]      = v0[t];
        dst[8 + t][tid]  = v1[t];
        dst[16 + t][tid] = v2[t];
        dst[24 + t][tid] = v3[t];
    }
}
// ---- MFMA 16x16x32 fragment from LDS panel
__device__ __forceinline__ bf16x8 frag(const __bf16 (*m)[264], int r0, int ks, int lane) {
    return *(const bf16x8*)&m[r0 + (lane & 15)][ks * 32 + ((lane >> 4) << 3)];
}

// ---------- K1: rep = elu(X @ Wfc^T + b) -> rep_bf (row-major) + rep_t (bh-major) ----------
__global__ __launch_bounds__(256) void k_fc(
    const float* __restrict__ X, const float* __restrict__ Wfc, const float* __restrict__ bfc,
    __bf16* __restrict__ rep_bf, __bf16* __restrict__ rep_t)
{
    __shared__ __bf16 Xa[32][264];
    __shared__ __bf16 Wb[32][264];
    const int tid = threadIdx.x, lane = tid & 63, wid = tid >> 6;
    const int mb = blockIdx.x >> 3, nb = blockIdx.x & 7;
    const int r0 = mb * 32, c0 = nb * 32;
    stage32f(X, r0, Xa, tid);
    stage32f(Wfc, c0, Wb, tid);
    __syncthreads();
    const int wr = (wid >> 1) * 16, wc = (wid & 1) * 16;
    f32x4 acc = {0.f, 0.f, 0.f, 0.f};
    #pragma unroll
    for (int ks = 0; ks < 8; ++ks)
        acc = __builtin_amdgcn_mfma_f32_16x16x32_bf16(frag(Xa, wr, ks, lane),
                                                      frag(Wb, wc, ks, lane), acc, 0, 0, 0);
    const int col = c0 + wc + (lane & 15);
    const int row = r0 + wr + ((lane >> 4) << 2);
    const int b = row >> 8, tok = row & 255;
    const float bv = bfc[col];
    bf16x4 pk;
    #pragma unroll
    for (int r = 0; r < 4; ++r) {
        float v = acc[r] + bv;
        v = (v > 0.f) ? v : (__expf(v) - 1.f);
        __bf16 h = (__bf16)v;
        rep_bf[(row + r) * DH + col] = h;
        pk[r] = h;
    }
    *(bf16x4*)(rep_t + ((b << 8) + col) * LQ + tok) = pk;
}

// ---------- K2: Ed = exp(0.4*(rep@W1^T+b1)), Eh = exp(0.4*rep@W2^T)  (bh-major f32) ----------
__global__ __launch_bounds__(256) void k_dephead(
    const __bf16* __restrict__ rep_bf, const float* __restrict__ W1, const float* __restrict__ W2,
    const float* __restrict__ b1, float* __restrict__ Ed_t, float* __restrict__ Eh_t)
{
    __shared__ __bf16 Ra[32][264];
    __shared__ __bf16 U1[32][264];
    __shared__ __bf16 U2[32][264];
    const int tid = threadIdx.x, lane = tid & 63, wid = tid >> 6;
    const int mb = blockIdx.x >> 3, nb = blockIdx.x & 7;
    const int r0 = mb * 32, c0 = nb * 32;
    stage32h(rep_bf, r0, Ra, tid);
    stage32f(W1, c0, U1, tid);
    stage32f(W2, c0, U2, tid);
    __syncthreads();
    const int wr = (wid >> 1) * 16, wc = (wid & 1) * 16;
    f32x4 ad = {0.f, 0.f, 0.f, 0.f}, ah = {0.f, 0.f, 0.f, 0.f};
    #pragma unroll
    for (int ks = 0; ks < 8; ++ks) {
        bf16x8 a = frag(Ra, wr, ks, lane);
        ad = __builtin_amdgcn_mfma_f32_16x16x32_bf16(a, frag(U1, wc, ks, lane), ad, 0, 0, 0);
        ah = __builtin_amdgcn_mfma_f32_16x16x32_bf16(a, frag(U2, wc, ks, lane), ah, 0, 0, 0);
    }
    const int col = c0 + wc + (lane & 15);
    const int row = r0 + wr + ((lane >> 4) << 2);
    const int b = row >> 8, tok = row & 255;
    const float bb = b1[col];
    f32x4 ed, eh;
    #pragma unroll
    for (int r = 0; r < 4; ++r) {
        ed[r] = __expf(0.4f * (ad[r] + bb));   // 2/C = 0.4
        eh[r] = __expf(0.4f * ah[r]);
    }
    *(f32x4*)(Ed_t + ((b << 8) + col) * LQ + tok) = ed;
    *(f32x4*)(Eh_t + ((b << 8) + col) * LQ + tok) = eh;
}

// ---------- K3: masked channel-softmax, j-split for occupancy ----------
// block = one bh, 256 thr = 4 waves. Wave (p=wv&1, hf=wv>>1): p selects w-set
// {0,3}/{1,2}; hf selects interleaved half of the jb blocks (stride 16). Each wave
// does a uniform 160 j-iters; halves combine via LDS partials.
__global__ __launch_bounds__(256) void k_attn(
    const float* __restrict__ Ed_t, const float* __restrict__ Eh_t,
    const __bf16* __restrict__ rep_t, __bf16* __restrict__ attn_t)
{
    __shared__ float Ed[256];
    __shared__ float Rp[256];
    __shared__ float sP[2][256];
    __shared__ float aP[2][256];
    const int bh = blockIdx.x;
    const int tid = threadIdx.x, lane = tid & 63, wv = tid >> 6;
    const int p = wv & 1, hf = wv >> 1;
    Ed[tid] = Ed_t[bh * LQ + tid];
    Rp[tid] = (float)rep_t[bh * LQ + tid];
    __syncthreads();
    const float A1 = -14.4269504f;             // -2C*log2(e)
    #pragma unroll
    for (int t = 0; t < 2; ++t) {
        const int w = p ? (t ? 2 : 1) : (t ? 3 : 0);
        const int i = w * 64 + lane;
        const float Eh = Eh_t[bh * LQ + i];
        float s = 0.f, acc = 0.f;
        // unmasked region: j in [(w+1)*64, 256), this wave's interleaved half
        for (int jb = 248 - 8 * hf; jb >= (w + 1) * 64; jb -= 16) {
            #pragma unroll
            for (int u = 0; u < 8; ++u) {
                const int j = jb + u;
                float r = __builtin_amdgcn_rcpf(fmaf(Ed[j], Eh, 1.f));
                float e = __builtin_amdgcn_exp2f(A1 * r);
                s += e;
                acc = fmaf(e, Rp[j], acc);
            }
        }
        // masked region: j in [w*64, w*64+64), this wave's half
        for (int jb = w * 64 + 56 - 8 * hf; jb >= w * 64; jb -= 16) {
            #pragma unroll
            for (int u = 0; u < 8; ++u) {
                const int j = jb + u;
                float r = __builtin_amdgcn_rcpf(fmaf(Ed[j], Eh, 1.f));
                float e = __builtin_amdgcn_exp2f(A1 * r);
                e = (j > i) ? e : 0.f;
                s += e;
                acc = fmaf(e, Rp[j], acc);
            }
        }
        sP[hf][i] = s;
        aP[hf][i] = acc;
    }
    __syncthreads();
    if (hf == 0) {
        #pragma unroll
        for (int t = 0; t < 2; ++t) {
            const int w = p ? (t ? 2 : 1) : (t ? 3 : 0);
            const int i = w * 64 + lane;
            float s = sP[0][i] + sP[1][i];
            float a = aP[0][i] + aP[1][i];
            attn_t[bh * LQ + i] = (__bf16)(a / (s + 1e-20f));
        }
    }
}

// ---------- K4: gate = sigmoid(rep@Wf1^T + attn@Wf2^T + bf); blend; mask ----------
__global__ __launch_bounds__(256) void k_gate(
    const __bf16* __restrict__ rep_bf, const __bf16* __restrict__ attn_t,
    const float* __restrict__ Wf1, const float* __restrict__ Wf2,
    const float* __restrict__ bfv, const float* __restrict__ rmask,
    float* __restrict__ out)
{
    __shared__ __bf16 Ra[32][264];
    __shared__ __bf16 Aa[32][264];
    __shared__ __bf16 U1[32][264];
    __shared__ __bf16 U2[32][264];
    const int tid = threadIdx.x, lane = tid & 63, wid = tid >> 6;
    const int mb = blockIdx.x >> 3, nb = blockIdx.x & 7;
    const int r0 = mb * 32, c0 = nb * 32;
    const int b = r0 >> 8, tok0 = r0 & 255;
    stage32h(rep_bf, r0, Ra, tid);
    stageT(attn_t, b, tok0, Aa, tid);
    stage32f(Wf1, c0, U1, tid);
    stage32f(Wf2, c0, U2, tid);
    __syncthreads();
    const int wr = (wid >> 1) * 16, wc = (wid & 1) * 16;
    f32x4 acc = {0.f, 0.f, 0.f, 0.f};
    #pragma unroll
    for (int ks = 0; ks < 8; ++ks) {
        acc = __builtin_amdgcn_mfma_f32_16x16x32_bf16(frag(Ra, wr, ks, lane),
                                                      frag(U1, wc, ks, lane), acc, 0, 0, 0);
        acc = __builtin_amdgcn_mfma_f32_16x16x32_bf16(frag(Aa, wr, ks, lane),
                                                      frag(U2, wc, ks, lane), acc, 0, 0, 0);
    }
    const int col = c0 + wc + (lane & 15);
    const int lr0 = wr + ((lane >> 4) << 2);
    const float bb = bfv[col];
    #pragma unroll
    for (int r = 0; r < 4; ++r) {
        const int lr = lr0 + r, rr = r0 + lr;
        float z = acc[r] + bb;
        float g = 1.f / (1.f + __expf(-z));
        float rv = (float)Ra[lr][col];
        float av = (float)Aa[lr][col];
        out[rr * DH + col] = (g * rv + (1.f - g) * av) * rmask[rr];
    }
}

extern "C" void kernel_launch(void* const* d_in, const int* in_sizes, int n_in,
                              void* d_out, int out_size, void* d_ws, size_t ws_size,
                              hipStream_t stream) {
    const float* x    = (const float*)d_in[0];
    const float* rmsk = (const float*)d_in[1];
    const float* fc_w = (const float*)d_in[2];
    const float* fc_b = (const float*)d_in[3];
    const float* w1   = (const float*)d_in[4];
    const float* w2   = (const float*)d_in[5];
    const float* b1   = (const float*)d_in[6];
    const float* wf1  = (const float*)d_in[7];
    const float* wf2  = (const float*)d_in[8];
    const float* bfb  = (const float*)d_in[9];

    char* ws = (char*)d_ws;
    __bf16* rep_bf  = (__bf16*)(ws);                  // 512 KB row-major
    __bf16* rep_t   = (__bf16*)(ws + (1u << 19));     // 512 KB bh-major
    __bf16* attn_t  = (__bf16*)(ws + (2u << 19));     // 512 KB bh-major
    float*  Ed_t    = (float*)(ws + (3u << 19));      // 1 MB bh-major
    float*  Eh_t    = (float*)(ws + (5u << 19));      // 1 MB bh-major

    k_fc<<<dim3(256), dim3(256), 0, stream>>>(x, fc_w, fc_b, rep_bf, rep_t);
    k_dephead<<<dim3(256), dim3(256), 0, stream>>>(rep_bf, w1, w2, b1, Ed_t, Eh_t);
    k_attn<<<dim3(1024), dim3(256), 0, stream>>>(Ed_t, Eh_t, rep_t, attn_t);
    k_gate<<<dim3(256), dim3(256), 0, stream>>>(rep_bf, attn_t, wf1, wf2, bfb, rmsk,
                                                (float*)d_out);
}

// Round 14
// 30.387 us; speedup vs baseline: 1.1098x; 1.0192x over previous
//
#include <hip/hip_runtime.h>

#define DH 256
#define LQ 256

typedef __bf16 bf16x8 __attribute__((ext_vector_type(8)));
typedef __bf16 bf16x4 __attribute__((ext_vector_type(4)));
typedef float  f32x4  __attribute__((ext_vector_type(4)));

__device__ __forceinline__ bf16x8 cvt2(float4 a, float4 b) {
    bf16x8 v;
    v[0] = (__bf16)a.x; v[1] = (__bf16)a.y; v[2] = (__bf16)a.z; v[3] = (__bf16)a.w;
    v[4] = (__bf16)b.x; v[5] = (__bf16)b.y; v[6] = (__bf16)b.z; v[7] = (__bf16)b.w;
    return v;
}

// ---- stage a 32-row x 256-col panel from f32 row-major global into LDS bf16 [32][264]
__device__ __forceinline__ void stage32f(const float* __restrict__ src, int row0,
                                         __bf16 (*dst)[264], int tid) {
    const int r = tid >> 3;
    #pragma unroll
    for (int c = 0; c < 4; ++c) {
        const int ch = (tid & 7) + 8 * c;
        const float* p = src + (row0 + r) * DH + ch * 8;
        *(bf16x8*)&dst[r][ch * 8] = cvt2(*(const float4*)p, *(const float4*)(p + 4));
    }
}
// ---- transposed stage: dst[tok_local][h] <- src[(b*256+h)*256 + tok0+tok_local], h = tid
__device__ __forceinline__ void stageT(const __bf16* __restrict__ src, int b, int tok0,
                                       __bf16 (*dst)[264], int tid) {
    const __bf16* p = src + (((b << 8) + tid) << 8) + tok0;
    bf16x8 v0 = *(const bf16x8*)(p);
    bf16x8 v1 = *(const bf16x8*)(p + 8);
    bf16x8 v2 = *(const bf16x8*)(p + 16);
    bf16x8 v3 = *(const bf16x8*)(p + 24);
    #pragma unroll
    for (int t = 0; t < 8; ++t) {
        dst[t][tid]      = v0[t];
        dst[8 + t][tid]  = v1[t];
        dst[16 + t][tid] = v2[t];
        dst[24 + t][tid] = v3[t];
    }
}
// ---- MFMA 16x16x32 fragment from LDS panel
__device__ __forceinline__ bf16x8 frag(const __bf16 (*m)[264], int r0, int ks, int lane) {
    return *(const bf16x8*)&m[r0 + (lane & 15)][ks * 32 + ((lane >> 4) << 3)];
}

// ---------- K1: rep = elu(X @ Wfc^T + b) -> rep_t (bh-major only) ----------
__global__ __launch_bounds__(256) void k_fc(
    const float* __restrict__ X, const float* __restrict__ Wfc, const float* __restrict__ bfc,
    __bf16* __restrict__ rep_t)
{
    __shared__ __bf16 Xa[32][264];
    __shared__ __bf16 Wb[32][264];
    const int tid = threadIdx.x, lane = tid & 63, wid = tid >> 6;
    const int mb = blockIdx.x >> 3, nb = blockIdx.x & 7;
    const int r0 = mb * 32, c0 = nb * 32;
    stage32f(X, r0, Xa, tid);
    stage32f(Wfc, c0, Wb, tid);
    __syncthreads();
    const int wr = (wid >> 1) * 16, wc = (wid & 1) * 16;
    f32x4 acc = {0.f, 0.f, 0.f, 0.f};
    #pragma unroll
    for (int ks = 0; ks < 8; ++ks)
        acc = __builtin_amdgcn_mfma_f32_16x16x32_bf16(frag(Xa, wr, ks, lane),
                                                      frag(Wb, wc, ks, lane), acc, 0, 0, 0);
    const int col = c0 + wc + (lane & 15);
    const int row = r0 + wr + ((lane >> 4) << 2);
    const int b = row >> 8, tok = row & 255;
    const float bv = bfc[col];
    bf16x4 pk;
    #pragma unroll
    for (int r = 0; r < 4; ++r) {
        float v = acc[r] + bv;
        v = (v > 0.f) ? v : (__expf(v) - 1.f);
        pk[r] = (__bf16)v;
    }
    *(bf16x4*)(rep_t + ((b << 8) + col) * LQ + tok) = pk;
}

// ---------- K2: Ed = exp(0.4*(rep@W1^T+b1)), Eh = exp(0.4*rep@W2^T)  (bh-major f32) ----------
__global__ __launch_bounds__(256) void k_dephead(
    const __bf16* __restrict__ rep_t, const float* __restrict__ W1, const float* __restrict__ W2,
    const float* __restrict__ b1, float* __restrict__ Ed_t, float* __restrict__ Eh_t)
{
    __shared__ __bf16 Ra[32][264];
    __shared__ __bf16 U1[32][264];
    __shared__ __bf16 U2[32][264];
    const int tid = threadIdx.x, lane = tid & 63, wid = tid >> 6;
    const int mb = blockIdx.x >> 3, nb = blockIdx.x & 7;
    const int r0 = mb * 32, c0 = nb * 32;
    const int bb0 = r0 >> 8, tok0 = r0 & 255;
    stageT(rep_t, bb0, tok0, Ra, tid);
    stage32f(W1, c0, U1, tid);
    stage32f(W2, c0, U2, tid);
    __syncthreads();
    const int wr = (wid >> 1) * 16, wc = (wid & 1) * 16;
    f32x4 ad = {0.f, 0.f, 0.f, 0.f}, ah = {0.f, 0.f, 0.f, 0.f};
    #pragma unroll
    for (int ks = 0; ks < 8; ++ks) {
        bf16x8 a = frag(Ra, wr, ks, lane);
        ad = __builtin_amdgcn_mfma_f32_16x16x32_bf16(a, frag(U1, wc, ks, lane), ad, 0, 0, 0);
        ah = __builtin_amdgcn_mfma_f32_16x16x32_bf16(a, frag(U2, wc, ks, lane), ah, 0, 0, 0);
    }
    const int col = c0 + wc + (lane & 15);
    const int row = r0 + wr + ((lane >> 4) << 2);
    const int b = row >> 8, tok = row & 255;
    const float bbias = b1[col];
    f32x4 ed, eh;
    #pragma unroll
    for (int r = 0; r < 4; ++r) {
        ed[r] = __expf(0.4f * (ad[r] + bbias));   // 2/C = 0.4
        eh[r] = __expf(0.4f * ah[r]);
    }
    *(f32x4*)(Ed_t + ((b << 8) + col) * LQ + tok) = ed;
    *(f32x4*)(Eh_t + ((b << 8) + col) * LQ + tok) = eh;
}

// ---------- K3: masked channel-softmax, j-split; e = exp2(rcp(fmaf(Ed, Eh/A1, 1/A1))) ----------
__global__ __launch_bounds__(256) void k_attn(
    const float* __restrict__ Ed_t, const float* __restrict__ Eh_t,
    const __bf16* __restrict__ rep_t, __bf16* __restrict__ attn_t)
{
    __shared__ float Ed[256];
    __shared__ float Rp[256];
    __shared__ float sP[2][256];
    __shared__ float aP[2][256];
    const int bh = blockIdx.x;
    const int tid = threadIdx.x, lane = tid & 63, wv = tid >> 6;
    const int p = wv & 1, hf = wv >> 1;
    Ed[tid] = Ed_t[bh * LQ + tid];
    Rp[tid] = (float)rep_t[bh * LQ + tid];
    __syncthreads();
    const float A1 = -14.4269504f;             // -2C*log2(e)
    const float CA = 1.f / A1;                 // 1/A1
    #pragma unroll
    for (int t = 0; t < 2; ++t) {
        const int w = p ? (t ? 2 : 1) : (t ? 3 : 0);
        const int i = w * 64 + lane;
        const float EhA = Eh_t[bh * LQ + i] * CA;   // Eh/A1
        float s = 0.f, acc = 0.f;
        // unmasked region: j in [(w+1)*64, 256), this wave's interleaved half
        for (int jb = 248 - 8 * hf; jb >= (w + 1) * 64; jb -= 16) {
            #pragma unroll
            for (int u = 0; u < 8; ++u) {
                const int j = jb + u;
                float r = __builtin_amdgcn_rcpf(fmaf(Ed[j], EhA, CA));
                float e = __builtin_amdgcn_exp2f(r);
                s += e;
                acc = fmaf(e, Rp[j], acc);
            }
        }
        // masked region: j in [w*64, w*64+64), this wave's half
        for (int jb = w * 64 + 56 - 8 * hf; jb >= w * 64; jb -= 16) {
            #pragma unroll
            for (int u = 0; u < 8; ++u) {
                const int j = jb + u;
                float r = __builtin_amdgcn_rcpf(fmaf(Ed[j], EhA, CA));
                float e = __builtin_amdgcn_exp2f(r);
                e = (j > i) ? e : 0.f;
                s += e;
                acc = fmaf(e, Rp[j], acc);
            }
        }
        sP[hf][i] = s;
        aP[hf][i] = acc;
    }
    __syncthreads();
    if (hf == 0) {
        #pragma unroll
        for (int t = 0; t < 2; ++t) {
            const int w = p ? (t ? 2 : 1) : (t ? 3 : 0);
            const int i = w * 64 + lane;
            float s = sP[0][i] + sP[1][i];
            float a = aP[0][i] + aP[1][i];
            attn_t[bh * LQ + i] = (__bf16)(a / (s + 1e-20f));
        }
    }
}

// ---------- K4: gate = sigmoid(rep@Wf1^T + attn@Wf2^T + bf); blend; mask ----------
__global__ __launch_bounds__(256) void k_gate(
    const __bf16* __restrict__ rep_t, const __bf16* __restrict__ attn_t,
    const float* __restrict__ Wf1, const float* __restrict__ Wf2,
    const float* __restrict__ bfv, const float* __restrict__ rmask,
    float* __restrict__ out)
{
    __shared__ __bf16 Ra[32][264];
    __shared__ __bf16 Aa[32][264];
    __shared__ __bf16 U1[32][264];
    __shared__ __bf16 U2[32][264];
    const int tid = threadIdx.x, lane = tid & 63, wid = tid >> 6;
    const int mb = blockIdx.x >> 3, nb = blockIdx.x & 7;
    const int r0 = mb * 32, c0 = nb * 32;
    const int b = r0 >> 8, tok0 = r0 & 255;
    stageT(rep_t, b, tok0, Ra, tid);
    stageT(attn_t, b, tok0, Aa, tid);
    stage32f(Wf1, c0, U1, tid);
    stage32f(Wf2, c0, U2, tid);
    __syncthreads();
    const int wr = (wid >> 1) * 16, wc = (wid & 1) * 16;
    f32x4 acc = {0.f, 0.f, 0.f, 0.f};
    #pragma unroll
    for (int ks = 0; ks < 8; ++ks) {
        acc = __builtin_amdgcn_mfma_f32_16x16x32_bf16(frag(Ra, wr, ks, lane),
                                                      frag(U1, wc, ks, lane), acc, 0, 0, 0);
        acc = __builtin_amdgcn_mfma_f32_16x16x32_bf16(frag(Aa, wr, ks, lane),
                                                      frag(U2, wc, ks, lane), acc, 0, 0, 0);
    }
    const int col = c0 + wc + (lane & 15);
    const int lr0 = wr + ((lane >> 4) << 2);
    const float bb = bfv[col];
    #pragma unroll
    for (int r = 0; r < 4; ++r) {
        const int lr = lr0 + r, rr = r0 + lr;
        float z = acc[r] + bb;
        float g = 1.f / (1.f + __expf(-z));
        float rv = (float)Ra[lr][col];
        float av = (float)Aa[lr][col];
        out[rr * DH + col] = (g * rv + (1.f - g) * av) * rmask[rr];
    }
}

extern "C" void kernel_launch(void* const* d_in, const int* in_sizes, int n_in,
                              void* d_out, int out_size, void* d_ws, size_t ws_size,
                              hipStream_t stream) {
    const float* x    = (const float*)d_in[0];
    const float* rmsk = (const float*)d_in[1];
    const float* fc_w = (const float*)d_in[2];
    const float* fc_b = (const float*)d_in[3];
    const float* w1   = (const float*)d_in[4];
    const float* w2   = (const float*)d_in[5];
    const float* b1   = (const float*)d_in[6];
    const float* wf1  = (const float*)d_in[7];
    const float* wf2  = (const float*)d_in[8];
    const float* bfb  = (const float*)d_in[9];

    char* ws = (char*)d_ws;
    __bf16* rep_t   = (__bf16*)(ws + (1u << 19));     // 512 KB bh-major
    __bf16* attn_t  = (__bf16*)(ws + (2u << 19));     // 512 KB bh-major
    float*  Ed_t    = (float*)(ws + (3u << 19));      // 1 MB bh-major
    float*  Eh_t    = (float*)(ws + (5u << 19));      // 1 MB bh-major

    k_fc<<<dim3(256), dim3(256), 0, stream>>>(x, fc_w, fc_b, rep_t);
    k_dephead<<<dim3(256), dim3(256), 0, stream>>>(rep_t, w1, w2, b1, Ed_t, Eh_t);
    k_attn<<<dim3(1024), dim3(256), 0, stream>>>(Ed_t, Eh_t, rep_t, attn_t);
    k_gate<<<dim3(256), dim3(256), 0, stream>>>(rep_t, attn_t, wf1, wf2, bfb, rmsk,
                                                (float*)d_out);
}